// Round 1
// baseline (1391.539 us; speedup 1.0000x reference)
//
#include <hip/hip_runtime.h>
#include <hip/hip_bf16.h>
#include <cstdint>

// Problem constants (B,S,D fixed by the reference)
static constexpr int ROWS = 4 * 1024;   // B*S = 4096
// layouts (all f32):
//  xn  : (4096, 1024)
//  z   : (4096, 1024)
//  xc  : (2, 4096, 1024)   branch-major (x1c, x2c)
//  dbc : (2*4096, 96)      [0:64)=delta_raw [64:80)=Bm [80:96)=Cm
//  delta:(2*4096, 1024)    softplus'd
//  y   : (2, 4, 1024, 1024)

// ---------------------------------------------------------------- LayerNorm + SiLU
__global__ __launch_bounds__(256) void ln_kernel(
    const float* __restrict__ x, const float* __restrict__ w,
    const float* __restrict__ b, float* __restrict__ xn, float* __restrict__ z) {
  const int row = blockIdx.x;
  const int tid = threadIdx.x;  // 256 threads, 4 floats each
  const float4 v = ((const float4*)(x + (size_t)row * 1024))[tid];
  float s  = v.x + v.y + v.z + v.w;
  float ss = v.x * v.x + v.y * v.y + v.z * v.z + v.w * v.w;
#pragma unroll
  for (int o = 32; o > 0; o >>= 1) {
    s  += __shfl_down(s, o);
    ss += __shfl_down(ss, o);
  }
  __shared__ float red[10];
  const int wid = tid >> 6, lane = tid & 63;
  if (lane == 0) { red[wid] = s; red[4 + wid] = ss; }
  __syncthreads();
  if (tid == 0) {
    const float S0 = red[0] + red[1] + red[2] + red[3];
    const float S1 = red[4] + red[5] + red[6] + red[7];
    const float mu = S0 * (1.0f / 1024.0f);
    const float var = S1 * (1.0f / 1024.0f) - mu * mu;
    red[8] = mu;
    red[9] = rsqrtf(var + 1e-5f);
  }
  __syncthreads();
  const float mu = red[8], rs = red[9];
  const float4 wv = ((const float4*)w)[tid];
  const float4 bv = ((const float4*)b)[tid];
  float4 o, zv;
  o.x = (v.x - mu) * rs * wv.x + bv.x;
  o.y = (v.y - mu) * rs * wv.y + bv.y;
  o.z = (v.z - mu) * rs * wv.z + bv.z;
  o.w = (v.w - mu) * rs * wv.w + bv.w;
  zv.x = o.x / (1.0f + __expf(-o.x));
  zv.y = o.y / (1.0f + __expf(-o.y));
  zv.z = o.z / (1.0f + __expf(-o.z));
  zv.w = o.w / (1.0f + __expf(-o.w));
  ((float4*)(xn + (size_t)row * 1024))[tid] = o;
  ((float4*)(z + (size_t)row * 1024))[tid] = zv;
}

// ---------------------------------------------------------------- generic f32 GEMM
// C[M][N] = A[M][K] * op(B) (+bias / +softplus / +Cadd)
// BT=true : B is (N,K) row-major (i.e. C = A @ B^T)
// ASUM    : A-operand = A + A2 (elementwise, on the fly)
// EPI: 0 none, 1 +bias[col], 2 softplus(acc+bias[col]), 3 +Cadd[row][col]
template <bool BT, int EPI, bool ASUM>
__global__ __launch_bounds__(256) void gemm_f32(
    const float* __restrict__ A, const float* __restrict__ A2,
    const float* __restrict__ B, const float* __restrict__ bias,
    const float* __restrict__ Cadd, float* __restrict__ C,
    int M, int N, int K, int lda, int ldb, int ldc) {
  constexpr int BM = 128, BN = 128, BK = 16, TM = 8, TN = 8;
  __shared__ float As[BK][BM + 4];
  __shared__ float Bs[BK][BN + 4];
  const int tid = threadIdx.x;
  const int tn = tid & 15;
  const int tm = tid >> 4;
  const int mbase = blockIdx.y * BM;
  const int nbase = blockIdx.x * BN;
  float acc[TM][TN];
#pragma unroll
  for (int i = 0; i < TM; ++i)
#pragma unroll
    for (int j = 0; j < TN; ++j) acc[i][j] = 0.0f;

  for (int kt = 0; kt < K; kt += BK) {
    // A tile: BM x BK, float4 along K, transposed into As[k][m]
#pragma unroll
    for (int i = 0; i < 2; ++i) {
      const int sidx = tid + i * 256;
      const int r = sidx >> 2, kc = (sidx & 3) << 2;
      float4 v = *(const float4*)(A + (size_t)(mbase + r) * lda + kt + kc);
      if constexpr (ASUM) {
        const float4 v2 = *(const float4*)(A2 + (size_t)(mbase + r) * lda + kt + kc);
        v.x += v2.x; v.y += v2.y; v.z += v2.z; v.w += v2.w;
      }
      As[kc + 0][r] = v.x; As[kc + 1][r] = v.y;
      As[kc + 2][r] = v.z; As[kc + 3][r] = v.w;
    }
    if constexpr (BT) {
#pragma unroll
      for (int i = 0; i < 2; ++i) {
        const int sidx = tid + i * 256;
        const int n = sidx >> 2, kc = (sidx & 3) << 2;
        const float4 v = *(const float4*)(B + (size_t)(nbase + n) * ldb + kt + kc);
        Bs[kc + 0][n] = v.x; Bs[kc + 1][n] = v.y;
        Bs[kc + 2][n] = v.z; Bs[kc + 3][n] = v.w;
      }
    } else {
#pragma unroll
      for (int i = 0; i < 2; ++i) {
        const int sidx = tid + i * 256;
        const int k = sidx >> 5, n4 = (sidx & 31) << 2;
        const float4 v = *(const float4*)(B + (size_t)(kt + k) * ldb + nbase + n4);
        *(float4*)&Bs[k][n4] = v;
      }
    }
    __syncthreads();
#pragma unroll
    for (int k = 0; k < BK; ++k) {
      float a[TM], bb_[TN];
      *(float4*)&a[0] = *(const float4*)&As[k][tm * TM];
      *(float4*)&a[4] = *(const float4*)&As[k][tm * TM + 4];
      *(float4*)&bb_[0] = *(const float4*)&Bs[k][tn * TN];
      *(float4*)&bb_[4] = *(const float4*)&Bs[k][tn * TN + 4];
#pragma unroll
      for (int i = 0; i < TM; ++i)
#pragma unroll
        for (int j = 0; j < TN; ++j) acc[i][j] = fmaf(a[i], bb_[j], acc[i][j]);
    }
    __syncthreads();
  }
#pragma unroll
  for (int i = 0; i < TM; ++i) {
    const int row = mbase + tm * TM + i;
#pragma unroll
    for (int j = 0; j < TN; ++j) {
      const int col = nbase + tn * TN + j;
      float v = acc[i][j];
      if constexpr (EPI == 1) v += bias[col];
      if constexpr (EPI == 2) {
        v += bias[col];
        v = (v > 20.0f) ? v : log1pf(__expf(v));  // softplus
      }
      if constexpr (EPI == 3) v += Cadd[(size_t)row * ldc + col];
      C[(size_t)row * ldc + col] = v;
    }
  }
}

// ---------------------------------------------------------------- skinny dbc GEMM
// out(8192,96) = X(8192,1024) @ W(96,1024)^T ; BM=32 rows/block for parallelism
__global__ __launch_bounds__(256) void dbc_kernel(
    const float* __restrict__ X, const float* __restrict__ W,
    float* __restrict__ out) {
  __shared__ float Xs[16][33];
  __shared__ float Ws[16][100];
  const int tid = threadIdx.x;
  const int rbase = blockIdx.x * 32;
  const int tn = tid & 15;   // 6 cols each
  const int tmq = tid >> 4;  // 2 rows each
  float acc[2][6];
#pragma unroll
  for (int q = 0; q < 2; ++q)
#pragma unroll
    for (int j = 0; j < 6; ++j) acc[q][j] = 0.0f;

  for (int kt = 0; kt < 1024; kt += 16) {
    if (tid < 128) {
      const int r = tid >> 2, kc = (tid & 3) << 2;
      const float4 v = *(const float4*)(X + (size_t)(rbase + r) * 1024 + kt + kc);
      Xs[kc + 0][r] = v.x; Xs[kc + 1][r] = v.y;
      Xs[kc + 2][r] = v.z; Xs[kc + 3][r] = v.w;
    }
#pragma unroll
    for (int i = 0; i < 2; ++i) {
      const int sidx = tid + i * 256;
      if (sidx < 384) {
        const int n = sidx >> 2, kc = (sidx & 3) << 2;
        const float4 v = *(const float4*)(W + (size_t)n * 1024 + kt + kc);
        Ws[kc + 0][n] = v.x; Ws[kc + 1][n] = v.y;
        Ws[kc + 2][n] = v.z; Ws[kc + 3][n] = v.w;
      }
    }
    __syncthreads();
#pragma unroll
    for (int k = 0; k < 16; ++k) {
      const float x0 = Xs[k][tmq * 2 + 0];
      const float x1 = Xs[k][tmq * 2 + 1];
#pragma unroll
      for (int j = 0; j < 6; ++j) {
        const float w = Ws[k][tn * 6 + j];
        acc[0][j] = fmaf(x0, w, acc[0][j]);
        acc[1][j] = fmaf(x1, w, acc[1][j]);
      }
    }
    __syncthreads();
  }
#pragma unroll
  for (int q = 0; q < 2; ++q) {
    const int r = rbase + tmq * 2 + q;
#pragma unroll
    for (int j = 0; j < 6; ++j) out[(size_t)r * 96 + tn * 6 + j] = acc[q][j];
  }
}

// ---------------------------------------------------------------- selective scan
// thread = (branch, b, d): 16 states in regs, sequential over l=0..1023
__global__ __launch_bounds__(256) void scan_kernel(
    const float* __restrict__ delta,  // (2*4096, 1024)
    const float* __restrict__ xc,     // (2*4096, 1024)
    const float* __restrict__ dbc,    // (8192, 96)
    const float* __restrict__ A_log,  // (1024, 16)
    const float* __restrict__ Dp,     // (1024)
    float* __restrict__ y) {          // (2*4096, 1024)
  const int d = blockIdx.x * 256 + threadIdx.x;
  const int b = blockIdx.y;
  const int br = blockIdx.z;
  const size_t rowbase = (size_t)br * 4096 + (size_t)b * 1024;
  float a[16];
#pragma unroll
  for (int n = 0; n < 16; ++n) a[n] = -__expf(A_log[(size_t)d * 16 + n]);
  const float dpv = Dp[d];
  float h[16];
#pragma unroll
  for (int n = 0; n < 16; ++n) h[n] = 0.0f;
  const float* dp_ = delta + rowbase * 1024 + d;
  const float* xp_ = xc + rowbase * 1024 + d;
  const float* bcp = dbc + rowbase * 96;
  float* yp = y + rowbase * 1024 + d;
  for (int l = 0; l < 1024; ++l) {
    const float dlt = dp_[(size_t)l * 1024];
    const float xv = xp_[(size_t)l * 1024];
    const float* bc = bcp + (size_t)l * 96;
    const float dx = dlt * xv;
    float yv = dpv * xv;
#pragma unroll
    for (int n = 0; n < 16; ++n) {
      const float dA = __expf(dlt * a[n]);
      h[n] = fmaf(dA, h[n], dx * bc[64 + n]);
      yv = fmaf(h[n], bc[80 + n], yv);
    }
    yp[(size_t)l * 1024] = yv;
  }
}

// ---------------------------------------------------------------- launch
extern "C" void kernel_launch(void* const* d_in, const int* in_sizes, int n_in,
                              void* d_out, int out_size, void* d_ws, size_t ws_size,
                              hipStream_t stream) {
  const float* x     = (const float*)d_in[0];
  const float* Wf    = (const float*)d_in[1];
  const float* bf    = (const float*)d_in[2];
  const float* Wb    = (const float*)d_in[3];
  const float* bb    = (const float*)d_in[4];
  const float* ln_w  = (const float*)d_in[5];
  const float* ln_b  = (const float*)d_in[6];
  const float* W_dbc = (const float*)d_in[7];
  const float* W_dt  = (const float*)d_in[8];
  const float* b_dt  = (const float*)d_in[9];
  const float* A_log = (const float*)d_in[10];
  const float* Dp    = (const float*)d_in[11];
  float* out = (float*)d_out;
  float* ws = (float*)d_ws;

  const size_t M1 = (size_t)1024 * 1024;
  float* z     = ws;             // 4*M1  [K1..K6]
  float* xc    = ws + 4 * M1;    // 8*M1  [K2..K5]
  float* delta = ws + 12 * M1;   // 8*M1  [K4..K5]
  float* xn    = ws + 12 * M1;   // 4*M1  [K1..K2]  (aliases delta; dead before K4)
  float* y     = ws + 20 * M1;   // 8*M1  [K5..K6]
  float* dbc   = ws + 28 * M1;   // 8192*96 [K3..K5]
  // total: (28M + 0.75M) floats ~= 115 MB of ws

  // K1: LayerNorm -> xn, z = silu(xn)
  ln_kernel<<<dim3(ROWS), dim3(256), 0, stream>>>(x, ln_w, ln_b, xn, z);

  // K2: xc[br] = xn @ W{f,b}^T + b{f,b}   (two 4096x1024x1024 GEMMs)
  gemm_f32<true, 1, false><<<dim3(8, 32), 256, 0, stream>>>(
      xn, nullptr, Wf, bf, nullptr, xc, 4096, 1024, 1024, 1024, 1024, 1024);
  gemm_f32<true, 1, false><<<dim3(8, 32), 256, 0, stream>>>(
      xn, nullptr, Wb, bb, nullptr, xc + 4 * M1, 4096, 1024, 1024, 1024, 1024, 1024);

  // K3: dbc = xc @ W_dbc^T   (8192x96x1024, skinny)
  dbc_kernel<<<dim3(256), 256, 0, stream>>>(xc, W_dbc, dbc);

  // K4: delta = softplus(dbc[:, :64] @ W_dt^T + b_dt)  (8192x1024x64)
  gemm_f32<true, 2, false><<<dim3(8, 64), 256, 0, stream>>>(
      dbc, nullptr, W_dt, b_dt, nullptr, delta, 8192, 1024, 64, 96, 64, 1024);

  // K5: selective scan, both branches
  scan_kernel<<<dim3(4, 4, 2), 256, 0, stream>>>(delta, xc, dbc, A_log, Dp, y);

  // K6: out[b] = (y1[b] + y2[b]) @ z[b] + x[b]   (4 batched 1024^3 GEMMs)
  for (int b = 0; b < 4; ++b) {
    gemm_f32<false, 3, true><<<dim3(8, 8), 256, 0, stream>>>(
        y + (size_t)b * M1, y + (size_t)(4 + b) * M1, z + (size_t)b * M1,
        nullptr, x + (size_t)b * M1, out + (size_t)b * M1,
        1024, 1024, 1024, 1024, 1024, 1024);
  }
}

// Round 2
// 254.712 us; speedup vs baseline: 5.4632x; 5.4632x over previous
//
#include <hip/hip_runtime.h>
#include <hip/hip_bf16.h>
#include <cstdint>

typedef __attribute__((ext_vector_type(8))) short bf16x8;
typedef __attribute__((ext_vector_type(4))) float f32x4;

__device__ inline unsigned short f2b(float f) {
  unsigned u = __builtin_bit_cast(unsigned, f);
  u += 0x7fffu + ((u >> 16) & 1u);
  return (unsigned short)(u >> 16);
}

__device__ inline void gload_lds16(const void* g, void* l) {
  __builtin_amdgcn_global_load_lds((const __attribute__((address_space(1))) void*)g,
                                   (__attribute__((address_space(3))) void*)l, 16, 0, 0);
}

// ---------------------------------------------------------------- LayerNorm -> xn(bf16), z=silu(xn)(bf16)
__global__ __launch_bounds__(256) void ln_kernel(
    const float* __restrict__ x, const float* __restrict__ w,
    const float* __restrict__ b, unsigned short* __restrict__ xnb,
    unsigned short* __restrict__ zb) {
  const int row = blockIdx.x;
  const int tid = threadIdx.x;
  const float4 v = ((const float4*)(x + (size_t)row * 1024))[tid];
  float s  = v.x + v.y + v.z + v.w;
  float ss = v.x * v.x + v.y * v.y + v.z * v.z + v.w * v.w;
#pragma unroll
  for (int o = 32; o > 0; o >>= 1) {
    s  += __shfl_down(s, o);
    ss += __shfl_down(ss, o);
  }
  __shared__ float red[10];
  const int wid = tid >> 6, lane = tid & 63;
  if (lane == 0) { red[wid] = s; red[4 + wid] = ss; }
  __syncthreads();
  if (tid == 0) {
    const float S0 = red[0] + red[1] + red[2] + red[3];
    const float S1 = red[4] + red[5] + red[6] + red[7];
    const float mu = S0 * (1.0f / 1024.0f);
    const float var = S1 * (1.0f / 1024.0f) - mu * mu;
    red[8] = mu;
    red[9] = rsqrtf(var + 1e-5f);
  }
  __syncthreads();
  const float mu = red[8], rs = red[9];
  const float4 wv = ((const float4*)w)[tid];
  const float4 bv = ((const float4*)b)[tid];
  float o0 = (v.x - mu) * rs * wv.x + bv.x;
  float o1 = (v.y - mu) * rs * wv.y + bv.y;
  float o2 = (v.z - mu) * rs * wv.z + bv.z;
  float o3 = (v.w - mu) * rs * wv.w + bv.w;
  ushort4 xo, zo;
  xo.x = f2b(o0); xo.y = f2b(o1); xo.z = f2b(o2); xo.w = f2b(o3);
  zo.x = f2b(o0 / (1.0f + __expf(-o0)));
  zo.y = f2b(o1 / (1.0f + __expf(-o1)));
  zo.z = f2b(o2 / (1.0f + __expf(-o2)));
  zo.w = f2b(o3 / (1.0f + __expf(-o3)));
  ((ushort4*)(xnb + (size_t)row * 1024))[tid] = xo;
  ((ushort4*)(zb + (size_t)row * 1024))[tid] = zo;
}

// ---------------------------------------------------------------- bf16 transpose per batch (z -> z^T)
__global__ __launch_bounds__(256) void transpose_bf16(
    const unsigned short* __restrict__ in, unsigned short* __restrict__ out) {
  __shared__ unsigned short t[32][33];
  const int tid = threadIdx.x;
  const int d0 = blockIdx.x * 32, s0 = blockIdx.y * 32;
  const size_t bb = (size_t)blockIdx.z * 1024 * 1024;
  const int lr = tid >> 3, lq = (tid & 7) * 4;
  const ushort4 v = *(const ushort4*)&in[bb + (size_t)(s0 + lr) * 1024 + d0 + lq];
  t[lr][lq + 0] = v.x; t[lr][lq + 1] = v.y; t[lr][lq + 2] = v.z; t[lr][lq + 3] = v.w;
  __syncthreads();
  ushort4 o;
  o.x = t[lq + 0][lr]; o.y = t[lq + 1][lr]; o.z = t[lq + 2][lr]; o.w = t[lq + 3][lr];
  *(ushort4*)&out[bb + (size_t)(d0 + lr) * 1024 + s0 + lq] = o;
}

// ---------------------------------------------------------------- f32 -> bf16 convert (with zero tail pad)
__global__ void convk(const float* __restrict__ s, unsigned short* __restrict__ o,
                      int nsrc, int ntot) {
  const int i = blockIdx.x * 256 + threadIdx.x;
  if (i < ntot) o[i] = (i < nsrc) ? f2b(s[i]) : (unsigned short)0;
}

__global__ void biascat(const float* __restrict__ a, const float* __restrict__ b,
                        float* __restrict__ o) {
  const int i = blockIdx.x * 256 + threadIdx.x;
  if (i < 2048) o[i] = (i < 1024) ? a[i] : b[i - 1024];
}

// ---------------------------------------------------------------- bf16 MFMA GEMM: C = A @ B^T (+epilogue)
// A: [M][K] bf16 row-major (lda), B: [N][K] bf16 row-major (ldb), C: f32 (ldc)
// EPI: 0 none, 1 +bias[col], 2 softplus(acc+bias[col]), 3 +Cadd[row][col]
// C2 (optional): bf16 copy of C for cols < n2 (ldc2)
template <int EPI>
__global__ __launch_bounds__(256) void gemm_mfma(
    const unsigned short* __restrict__ A, const unsigned short* __restrict__ B,
    const float* __restrict__ bias, const float* __restrict__ Cadd,
    float* __restrict__ C, unsigned short* __restrict__ C2,
    int K, int lda, int ldb, int ldc, int ldc2, int n2,
    size_t astride, size_t bstride, size_t cstride, size_t addstride,
    size_t biasstride, size_t c2stride) {
  __shared__ unsigned short As[128 * 32];
  __shared__ unsigned short Bs[128 * 32];
  const int tid = threadIdx.x;
  const int lane = tid & 63;
  const int wid = tid >> 6;
  const int wm = wid >> 1, wn = wid & 1;
  const int mbase = blockIdx.y * 128;
  const int nbase = blockIdx.x * 128;
  const size_t zz = blockIdx.z;
  A += zz * astride;
  B += zz * bstride;
  C += zz * cstride;
  if (EPI == 3) Cadd += zz * addstride;
  if (EPI == 1 || EPI == 2) bias += zz * biasstride;
  if (C2) C2 += zz * c2stride;

  f32x4 acc[4][4];
#pragma unroll
  for (int i = 0; i < 4; ++i)
#pragma unroll
    for (int j = 0; j < 4; ++j) acc[i][j] = (f32x4){0.f, 0.f, 0.f, 0.f};

  const int r0 = tid >> 2;            // 0..63
  const int ch0 = (tid & 3) * 8;      // k-chunk of 8 bf16 (16B)

  for (int kt = 0; kt < K; kt += 32) {
    gload_lds16(A + (size_t)(mbase + r0) * lda + kt + ch0, &As[(size_t)tid * 8]);
    gload_lds16(A + (size_t)(mbase + r0 + 64) * lda + kt + ch0, &As[((size_t)tid + 256) * 8]);
    gload_lds16(B + (size_t)(nbase + r0) * ldb + kt + ch0, &Bs[(size_t)tid * 8]);
    gload_lds16(B + (size_t)(nbase + r0 + 64) * ldb + kt + ch0, &Bs[((size_t)tid + 256) * 8]);
    __syncthreads();
    bf16x8 af[4], bfr[4];
    const int arow = wm * 64 + (lane & 15);
    const int brow = wn * 64 + (lane & 15);
    const int kofs = (lane >> 4) * 8;
#pragma unroll
    for (int mi = 0; mi < 4; ++mi) af[mi] = *(const bf16x8*)&As[(size_t)(arow + mi * 16) * 32 + kofs];
#pragma unroll
    for (int ni = 0; ni < 4; ++ni) bfr[ni] = *(const bf16x8*)&Bs[(size_t)(brow + ni * 16) * 32 + kofs];
#pragma unroll
    for (int mi = 0; mi < 4; ++mi)
#pragma unroll
      for (int ni = 0; ni < 4; ++ni)
        acc[mi][ni] = __builtin_amdgcn_mfma_f32_16x16x32_bf16(af[mi], bfr[ni], acc[mi][ni], 0, 0, 0);
    __syncthreads();
  }

  const int lrow = (lane >> 4) * 4, lcol = lane & 15;
#pragma unroll
  for (int mi = 0; mi < 4; ++mi) {
#pragma unroll
    for (int ni = 0; ni < 4; ++ni) {
      const int col = nbase + wn * 64 + ni * 16 + lcol;
      const int row0 = mbase + wm * 64 + mi * 16 + lrow;
#pragma unroll
      for (int r = 0; r < 4; ++r) {
        float v = acc[mi][ni][r];
        const int row = row0 + r;
        if (EPI == 1) v += bias[col];
        if (EPI == 2) {
          v += bias[col];
          v = (v > 20.f) ? v : log1pf(__expf(v));
        }
        if (EPI == 3) v += Cadd[(size_t)row * ldc + col];
        C[(size_t)row * ldc + col] = v;
        if (C2 && col < n2) C2[(size_t)row * ldc2 + col] = f2b(v);
      }
    }
  }
}

// ---------------------------------------------------------------- scan pass A: per-chunk local scan
// cs layout: [z=8][chunk=32][slot=32][d=1024]; slot n = Ap, slot 16+n = h_end
__global__ __launch_bounds__(256) void scan_a(
    const float* __restrict__ delta, const float* __restrict__ xc,
    const float* __restrict__ dbc, const float* __restrict__ A_log,
    float* __restrict__ cs) {
  const int tid = threadIdx.x;
  const int d = blockIdx.x * 256 + tid;
  const int chunk = blockIdx.y;
  const int z = blockIdx.z;
  __shared__ float sB[32][16];
  for (int i = tid; i < 512; i += 256) {
    const int l = i >> 4, n = i & 15;
    sB[l][n] = dbc[(size_t)(z * 1024 + chunk * 32 + l) * 128 + 64 + n];
  }
  __syncthreads();
  float a[16], h[16];
#pragma unroll
  for (int n = 0; n < 16; ++n) {
    a[n] = -__expf(A_log[d * 16 + n]);
    h[n] = 0.0f;
  }
  float sdlt = 0.0f;
  const size_t rbase = (size_t)(z * 1024 + chunk * 32) * 1024 + d;
  for (int l = 0; l < 32; ++l) {
    const float dlt = delta[rbase + (size_t)l * 1024];
    const float xv  = xc[rbase + (size_t)l * 1024];
    const float dx = dlt * xv;
    sdlt += dlt;
#pragma unroll
    for (int n = 0; n < 16; ++n)
      h[n] = fmaf(__expf(dlt * a[n]), h[n], dx * sB[l][n]);
  }
  const size_t cbase = ((size_t)(z * 32 + chunk) * 32) * 1024 + d;
#pragma unroll
  for (int n = 0; n < 16; ++n) {
    cs[cbase + (size_t)n * 1024] = __expf(a[n] * sdlt);
    cs[cbase + (size_t)(16 + n) * 1024] = h[n];
  }
}

// ---------------------------------------------------------------- scan pass B: inter-chunk scan
// overwrites the Ap slot with h_start for that chunk
__global__ __launch_bounds__(256) void scan_b(float* __restrict__ cs) {
  const int tid = threadIdx.x;
  const int d = blockIdx.x * 64 + (tid & 63);
  const int n = blockIdx.y * 4 + (tid >> 6);
  const int z = blockIdx.z;
  float h = 0.0f;
  for (int c = 0; c < 32; ++c) {
    const size_t base = ((size_t)(z * 32 + c) * 32) * 1024 + d;
    const float Ap = cs[base + (size_t)n * 1024];
    const float he = cs[base + (size_t)(16 + n) * 1024];
    cs[base + (size_t)n * 1024] = h;
    h = fmaf(Ap, h, he);
  }
}

// ---------------------------------------------------------------- scan pass C: recompute with h_start, emit y
// BR: branch. OUTB=0: y f32 := yv ; OUTB=1: yb bf16 := y + yv (fuses y1+y2)
template <int BR, int OUTB>
__global__ __launch_bounds__(256) void scan_c(
    const float* __restrict__ delta, const float* __restrict__ xc,
    const float* __restrict__ dbc, const float* __restrict__ A_log,
    const float* __restrict__ Dp, const float* __restrict__ cs,
    float* __restrict__ y, unsigned short* __restrict__ yb) {
  const int tid = threadIdx.x;
  const int d = blockIdx.x * 256 + tid;
  const int chunk = blockIdx.y;
  const int b = blockIdx.z;
  const int z = BR * 4 + b;
  __shared__ float sBC[32][32];
  for (int i = tid; i < 1024; i += 256) {
    const int l = i >> 5, c = i & 31;
    sBC[l][c] = dbc[(size_t)(z * 1024 + chunk * 32 + l) * 128 + 64 + c];
  }
  __syncthreads();
  float a[16], h[16];
  const size_t cbase = ((size_t)(z * 32 + chunk) * 32) * 1024 + d;
#pragma unroll
  for (int n = 0; n < 16; ++n) {
    a[n] = -__expf(A_log[d * 16 + n]);
    h[n] = cs[cbase + (size_t)n * 1024];
  }
  const float dpv = Dp[d];
  const size_t rbase = (size_t)(z * 1024 + chunk * 32) * 1024 + d;
  const size_t ybase = (size_t)(b * 1024 + chunk * 32) * 1024 + d;
  for (int l = 0; l < 32; ++l) {
    const float dlt = delta[rbase + (size_t)l * 1024];
    const float xv  = xc[rbase + (size_t)l * 1024];
    const float dx = dlt * xv;
    float yv = dpv * xv;
#pragma unroll
    for (int n = 0; n < 16; ++n) {
      h[n] = fmaf(__expf(dlt * a[n]), h[n], dx * sBC[l][n]);
      yv = fmaf(h[n], sBC[l][16 + n], yv);
    }
    if (OUTB)
      yb[ybase + (size_t)l * 1024] = f2b(y[ybase + (size_t)l * 1024] + yv);
    else
      y[ybase + (size_t)l * 1024] = yv;
  }
}

// ---------------------------------------------------------------- launch
extern "C" void kernel_launch(void* const* d_in, const int* in_sizes, int n_in,
                              void* d_out, int out_size, void* d_ws, size_t ws_size,
                              hipStream_t stream) {
  const float* x     = (const float*)d_in[0];
  const float* Wf    = (const float*)d_in[1];
  const float* bf    = (const float*)d_in[2];
  const float* Wb    = (const float*)d_in[3];
  const float* bb    = (const float*)d_in[4];
  const float* ln_w  = (const float*)d_in[5];
  const float* ln_b  = (const float*)d_in[6];
  const float* W_dbc = (const float*)d_in[7];
  const float* W_dt  = (const float*)d_in[8];
  const float* b_dt  = (const float*)d_in[9];
  const float* A_log = (const float*)d_in[10];
  const float* Dp    = (const float*)d_in[11];
  float* out = (float*)d_out;
  char* wsb = (char*)d_ws;

  const size_t MB = 1024 * 1024;
  const size_t M1 = 1048576;  // 1024*1024 elements
  // byte offsets into ws
  unsigned short* zTb   = (unsigned short*)(wsb + 0);         //  8 MB  [zT .. K6]
  float*          xc    = (float*)(wsb + 8 * MB);             // 32 MB  [K2 .. scanC]
  unsigned short* xcb   = (unsigned short*)(wsb + 40 * MB);   // 16 MB  [K2 .. K3]
  float*          y     = (float*)(wsb + 40 * MB);            // 16 MB  [scanC0 .. scanC1] (overlays xcb)
  float*          dbc   = (float*)(wsb + 56 * MB);            //  4 MB  [K3 .. scanC]
  unsigned short* dbcd  = (unsigned short*)(wsb + 60 * MB);   //  1 MB  [K3 .. K4]
  unsigned short* Wfb   = (unsigned short*)(wsb + 61 * MB);   //  4 MB
  unsigned short* Wdbcb = (unsigned short*)(wsb + 65 * MB);   //  0.25 MB (128x1024, zero-padded)
  unsigned short* Wdtb  = (unsigned short*)(wsb + 65 * MB + 256 * 1024);  // 0.125 MB
  float*          bias2 = (float*)(wsb + 65 * MB + 384 * 1024);           // 8 KB
  float*          delta = (float*)(wsb + 66 * MB);            // 32 MB  [K4 .. scanC]
  unsigned short* xnb   = (unsigned short*)(wsb + 66 * MB);   //  8 MB  [LN .. K2] (overlays delta)
  unsigned short* zb    = (unsigned short*)(wsb + 74 * MB);   //  8 MB  [LN .. zT] (overlays delta)
  float*          cs    = (float*)(wsb + 98 * MB);            // 32 MB  [scanA .. scanC]
  unsigned short* Asum  = (unsigned short*)(wsb + 130 * MB);  //  8 MB  [scanC1 .. K6]
  // total 138 MB

  // 1) LayerNorm -> xn(bf16), z(bf16)
  ln_kernel<<<dim3(4096), dim3(256), 0, stream>>>(x, ln_w, ln_b, xnb, zb);
  // 2) z^T per batch
  transpose_bf16<<<dim3(32, 32, 4), dim3(256), 0, stream>>>(zb, zTb);
  // 3) weight converts
  convk<<<dim3(4096), dim3(256), 0, stream>>>(Wf, Wfb, 1048576, 1048576);
  convk<<<dim3(4096), dim3(256), 0, stream>>>(Wb, Wfb + M1, 1048576, 1048576);
  convk<<<dim3(512),  dim3(256), 0, stream>>>(W_dbc, Wdbcb, 98304, 131072);
  convk<<<dim3(256),  dim3(256), 0, stream>>>(W_dt, Wdtb, 65536, 65536);
  biascat<<<dim3(8), dim3(256), 0, stream>>>(bf, bb, bias2);

  // 4) K2: xc[br] = xn @ W{f,b}^T + bias   (z-dim = branch; A shared)
  gemm_mfma<1><<<dim3(8, 32, 2), dim3(256), 0, stream>>>(
      xnb, Wfb, bias2, nullptr, xc, xcb,
      1024, 1024, 1024, 1024, 1024, 1024,
      0, M1, 4 * M1, 0, 1024, 4 * M1);

  // 5) K3: dbc = xc @ W_dbc^T (N padded to 128); bf16 copy of delta-part
  gemm_mfma<0><<<dim3(1, 64, 1), dim3(256), 0, stream>>>(
      xcb, Wdbcb, nullptr, nullptr, dbc, dbcd,
      1024, 1024, 1024, 128, 64, 64,
      0, 0, 0, 0, 0, 0);

  // 6) K4: delta = softplus(dbc_delta @ W_dt^T + b_dt)
  gemm_mfma<2><<<dim3(8, 64, 1), dim3(256), 0, stream>>>(
      dbcd, Wdtb, b_dt, nullptr, delta, nullptr,
      64, 64, 64, 1024, 0, 0,
      0, 0, 0, 0, 0, 0);

  // 7) chunked selective scan
  scan_a<<<dim3(4, 32, 8), dim3(256), 0, stream>>>(delta, xc, dbc, A_log, cs);
  scan_b<<<dim3(16, 4, 8), dim3(256), 0, stream>>>(cs);
  scan_c<0, 0><<<dim3(4, 32, 4), dim3(256), 0, stream>>>(delta, xc, dbc, A_log, Dp, cs, y, nullptr);
  scan_c<1, 1><<<dim3(4, 32, 4), dim3(256), 0, stream>>>(delta, xc, dbc, A_log, Dp, cs, y, Asum);

  // 8) K6: out[b] = (y1+y2)[b] @ z[b] + x[b]
  gemm_mfma<3><<<dim3(8, 8, 4), dim3(256), 0, stream>>>(
      Asum, zTb, nullptr, x, out, nullptr,
      1024, 1024, 1024, 1024, 0, 0,
      M1, M1, M1, M1, 0, 0);
}

// Round 3
// 216.606 us; speedup vs baseline: 6.4243x; 1.1759x over previous
//
#include <hip/hip_runtime.h>
#include <hip/hip_bf16.h>
#include <cstdint>

typedef __attribute__((ext_vector_type(8))) short bf16x8;
typedef __attribute__((ext_vector_type(4))) float f32x4;

__device__ inline unsigned short f2b(float f) {
  unsigned u = __builtin_bit_cast(unsigned, f);
  u += 0x7fffu + ((u >> 16) & 1u);
  return (unsigned short)(u >> 16);
}
__device__ inline float b2f(unsigned short u) {
  return __builtin_bit_cast(float, (unsigned)u << 16);
}
__device__ inline void gload_lds16(const void* g, void* l) {
  __builtin_amdgcn_global_load_lds((const __attribute__((address_space(1))) void*)g,
                                   (__attribute__((address_space(3))) void*)l, 16, 0, 0);
}

// ---------------------------------------------------------------- LayerNorm -> xn(bf16), z=silu(xn)(bf16)
__global__ __launch_bounds__(256) void ln_kernel(
    const float* __restrict__ x, const float* __restrict__ w,
    const float* __restrict__ b, unsigned short* __restrict__ xnb,
    unsigned short* __restrict__ zb) {
  const int row = blockIdx.x;
  const int tid = threadIdx.x;
  const float4 v = ((const float4*)(x + (size_t)row * 1024))[tid];
  float s  = v.x + v.y + v.z + v.w;
  float ss = v.x * v.x + v.y * v.y + v.z * v.z + v.w * v.w;
#pragma unroll
  for (int o = 32; o > 0; o >>= 1) {
    s  += __shfl_down(s, o);
    ss += __shfl_down(ss, o);
  }
  __shared__ float red[10];
  const int wid = tid >> 6, lane = tid & 63;
  if (lane == 0) { red[wid] = s; red[4 + wid] = ss; }
  __syncthreads();
  if (tid == 0) {
    const float S0 = red[0] + red[1] + red[2] + red[3];
    const float S1 = red[4] + red[5] + red[6] + red[7];
    const float mu = S0 * (1.0f / 1024.0f);
    const float var = S1 * (1.0f / 1024.0f) - mu * mu;
    red[8] = mu;
    red[9] = rsqrtf(var + 1e-5f);
  }
  __syncthreads();
  const float mu = red[8], rs = red[9];
  const float4 wv = ((const float4*)w)[tid];
  const float4 bv = ((const float4*)b)[tid];
  float o0 = (v.x - mu) * rs * wv.x + bv.x;
  float o1 = (v.y - mu) * rs * wv.y + bv.y;
  float o2 = (v.z - mu) * rs * wv.z + bv.z;
  float o3 = (v.w - mu) * rs * wv.w + bv.w;
  ushort4 xo, zo;
  xo.x = f2b(o0); xo.y = f2b(o1); xo.z = f2b(o2); xo.w = f2b(o3);
  zo.x = f2b(o0 / (1.0f + __expf(-o0)));
  zo.y = f2b(o1 / (1.0f + __expf(-o1)));
  zo.z = f2b(o2 / (1.0f + __expf(-o2)));
  zo.w = f2b(o3 / (1.0f + __expf(-o3)));
  ((ushort4*)(xnb + (size_t)row * 1024))[tid] = xo;
  ((ushort4*)(zb + (size_t)row * 1024))[tid] = zo;
}

// ---------------------------------------------------------------- bf16 transpose per batch (z -> z^T)
__global__ __launch_bounds__(256) void transpose_bf16(
    const unsigned short* __restrict__ in, unsigned short* __restrict__ out) {
  __shared__ unsigned short t[32][33];
  const int tid = threadIdx.x;
  const int d0 = blockIdx.x * 32, s0 = blockIdx.y * 32;
  const size_t bb = (size_t)blockIdx.z * 1024 * 1024;
  const int lr = tid >> 3, lq = (tid & 7) * 4;
  const ushort4 v = *(const ushort4*)&in[bb + (size_t)(s0 + lr) * 1024 + d0 + lq];
  t[lr][lq + 0] = v.x; t[lr][lq + 1] = v.y; t[lr][lq + 2] = v.z; t[lr][lq + 3] = v.w;
  __syncthreads();
  ushort4 o;
  o.x = t[lq + 0][lr]; o.y = t[lq + 1][lr]; o.z = t[lq + 2][lr]; o.w = t[lq + 3][lr];
  *(ushort4*)&out[bb + (size_t)(d0 + lr) * 1024 + s0 + lq] = o;
}

// ---------------------------------------------------------------- fused weight prep
// ranges: Wf->Wfb[0:1M), Wb->Wfb[1M:2M), W_dbc pad128->Wdbcb, W_dt->Wdtb,
//         bias2 = [bf | bb], a_tab = -exp(A_log)
__global__ void prep(const float* __restrict__ Wf, const float* __restrict__ Wb,
                     const float* __restrict__ W_dbc, const float* __restrict__ W_dt,
                     const float* __restrict__ bf_, const float* __restrict__ bb_,
                     const float* __restrict__ A_log,
                     unsigned short* __restrict__ Wfb, unsigned short* __restrict__ Wdbcb,
                     unsigned short* __restrict__ Wdtb, float* __restrict__ bias2,
                     float* __restrict__ a_tab) {
  const int i = blockIdx.x * 256 + threadIdx.x;
  if (i < 1048576) {
    Wfb[i] = f2b(Wf[i]);
  } else if (i < 2097152) {
    Wfb[i] = f2b(Wb[i - 1048576]);
  } else if (i < 2228224) {
    const int j = i - 2097152;
    Wdbcb[j] = (j < 98304) ? f2b(W_dbc[j]) : (unsigned short)0;
  } else if (i < 2293760) {
    const int j = i - 2228224;
    Wdtb[j] = f2b(W_dt[j]);
  } else if (i < 2295808) {
    const int j = i - 2293760;
    bias2[j] = (j < 1024) ? bf_[j] : bb_[j - 1024];
  } else if (i < 2312192) {
    const int j = i - 2295808;
    a_tab[j] = -__expf(A_log[j]);
  }
}

// ---------------------------------------------------------------- bf16 MFMA GEMM: C = A @ B^T (+epilogue)
// A:[M][K] bf16 (lda), B:[N][K] bf16 (ldb). C f32 (optional), C2 bf16 (optional, cols<n2).
// EPI: 0 none, 1 +bias[col], 2 softplus(acc+bias[col]), 3 +Cadd[row][col]
template <int EPI, int BM, int BN>
__global__ __launch_bounds__(256) void gemm_mfma(
    const unsigned short* __restrict__ A, const unsigned short* __restrict__ B,
    const float* __restrict__ bias, const float* __restrict__ Cadd,
    float* __restrict__ C, unsigned short* __restrict__ C2,
    int K, int lda, int ldb, int ldc, int ldc2, int n2,
    size_t astride, size_t bstride, size_t cstride, size_t addstride,
    size_t biasstride, size_t c2stride) {
  constexpr int WTM = BM / 32;  // 16x16 acc tiles per wave (m)
  constexpr int WTN = BN / 32;
  __shared__ unsigned short As[BM * 32];
  __shared__ unsigned short Bs[BN * 32];
  const int tid = threadIdx.x;
  const int lane = tid & 63;
  const int wid = tid >> 6;
  const int wm = wid >> 1, wn = wid & 1;
  const int mbase = blockIdx.y * BM;
  const int nbase = blockIdx.x * BN;
  const size_t zz = blockIdx.z;
  A += zz * astride;
  B += zz * bstride;
  if (C) C += zz * cstride;
  if (EPI == 3) Cadd += zz * addstride;
  if (EPI == 1 || EPI == 2) bias += zz * biasstride;
  if (C2) C2 += zz * c2stride;

  f32x4 acc[WTM][WTN];
#pragma unroll
  for (int i = 0; i < WTM; ++i)
#pragma unroll
    for (int j = 0; j < WTN; ++j) acc[i][j] = (f32x4){0.f, 0.f, 0.f, 0.f};

  const int r0 = tid >> 2;        // 0..63
  const int ch0 = (tid & 3) * 8;  // 16B k-chunk

  for (int kt = 0; kt < K; kt += 32) {
#pragma unroll
    for (int i = 0; i < BM / 64; ++i)
      gload_lds16(A + (size_t)(mbase + r0 + i * 64) * lda + kt + ch0,
                  &As[((size_t)tid + i * 256) * 8]);
#pragma unroll
    for (int i = 0; i < BN / 64; ++i)
      gload_lds16(B + (size_t)(nbase + r0 + i * 64) * ldb + kt + ch0,
                  &Bs[((size_t)tid + i * 256) * 8]);
    __syncthreads();
    const int arow = wm * (BM / 2) + (lane & 15);
    const int brow = wn * (BN / 2) + (lane & 15);
    const int kofs = (lane >> 4) * 8;
    bf16x8 af[WTM], bfr[WTN];
#pragma unroll
    for (int mi = 0; mi < WTM; ++mi) af[mi] = *(const bf16x8*)&As[(size_t)(arow + mi * 16) * 32 + kofs];
#pragma unroll
    for (int ni = 0; ni < WTN; ++ni) bfr[ni] = *(const bf16x8*)&Bs[(size_t)(brow + ni * 16) * 32 + kofs];
#pragma unroll
    for (int mi = 0; mi < WTM; ++mi)
#pragma unroll
      for (int ni = 0; ni < WTN; ++ni)
        acc[mi][ni] = __builtin_amdgcn_mfma_f32_16x16x32_bf16(af[mi], bfr[ni], acc[mi][ni], 0, 0, 0);
    __syncthreads();
  }

  const int lrow = (lane >> 4) * 4, lcol = lane & 15;
#pragma unroll
  for (int mi = 0; mi < WTM; ++mi) {
#pragma unroll
    for (int ni = 0; ni < WTN; ++ni) {
      const int col = nbase + wn * (BN / 2) + ni * 16 + lcol;
      const int row0 = mbase + wm * (BM / 2) + mi * 16 + lrow;
#pragma unroll
      for (int r = 0; r < 4; ++r) {
        float v = acc[mi][ni][r];
        const int row = row0 + r;
        if (EPI == 1) v += bias[col];
        if (EPI == 2) {
          v += bias[col];
          v = (v > 20.f) ? v : log1pf(__expf(v));
        }
        if (EPI == 3) v += Cadd[(size_t)row * ldc + col];
        if (C) C[(size_t)row * ldc + col] = v;
        if (C2 && col < n2) C2[(size_t)row * ldc2 + col] = f2b(v);
      }
    }
  }
}

// ---------------------------------------------------------------- scan pass A: per-chunk local scan
// cs layout: [z=8][chunk=32][slot=32][d=1024]; slot n = Ap, slot 16+n = h_end
__global__ __launch_bounds__(256) void scan_a(
    const unsigned short* __restrict__ delta, const unsigned short* __restrict__ xc,
    const float* __restrict__ dbc, const float* __restrict__ a_tab,
    float* __restrict__ cs) {
  const int tid = threadIdx.x;
  const int d = blockIdx.x * 256 + tid;
  const int chunk = blockIdx.y;
  const int z = blockIdx.z;
  __shared__ float sB[32][16];
  for (int i = tid; i < 512; i += 256) {
    const int l = i >> 4, n = i & 15;
    sB[l][n] = dbc[(size_t)(z * 1024 + chunk * 32 + l) * 128 + 64 + n];
  }
  __syncthreads();
  float a[16], h[16];
#pragma unroll
  for (int n = 0; n < 16; ++n) {
    a[n] = a_tab[d * 16 + n];
    h[n] = 0.0f;
  }
  float sdlt = 0.0f;
  const size_t rbase = (size_t)(z * 1024 + chunk * 32) * 1024 + d;
  for (int l = 0; l < 32; ++l) {
    const float dlt = b2f(delta[rbase + (size_t)l * 1024]);
    const float xv  = b2f(xc[rbase + (size_t)l * 1024]);
    const float dx = dlt * xv;
    sdlt += dlt;
#pragma unroll
    for (int n = 0; n < 16; ++n)
      h[n] = fmaf(__expf(dlt * a[n]), h[n], dx * sB[l][n]);
  }
  const size_t cbase = ((size_t)(z * 32 + chunk) * 32) * 1024 + d;
#pragma unroll
  for (int n = 0; n < 16; ++n) {
    cs[cbase + (size_t)n * 1024] = __expf(a[n] * sdlt);
    cs[cbase + (size_t)(16 + n) * 1024] = h[n];
  }
}

// ---------------------------------------------------------------- scan pass B: inter-chunk scan
__global__ __launch_bounds__(256) void scan_b(float* __restrict__ cs) {
  const int tid = threadIdx.x;
  const int d = blockIdx.x * 64 + (tid & 63);
  const int n = blockIdx.y * 4 + (tid >> 6);
  const int z = blockIdx.z;
  float h = 0.0f;
  for (int c = 0; c < 32; ++c) {
    const size_t base = ((size_t)(z * 32 + c) * 32) * 1024 + d;
    const float Ap = cs[base + (size_t)n * 1024];
    const float he = cs[base + (size_t)(16 + n) * 1024];
    cs[base + (size_t)n * 1024] = h;
    h = fmaf(Ap, h, he);
  }
}

// ---------------------------------------------------------------- scan pass C (both branches fused):
// recompute with h_start, emit Asum = y1 + y2 (bf16)
__global__ __launch_bounds__(256) void scan_c(
    const unsigned short* __restrict__ delta, const unsigned short* __restrict__ xc,
    const float* __restrict__ dbc, const float* __restrict__ a_tab,
    const float* __restrict__ Dp, const float* __restrict__ cs,
    unsigned short* __restrict__ yb) {
  const int tid = threadIdx.x;
  const int d = blockIdx.x * 256 + tid;
  const int chunk = blockIdx.y;
  const int b = blockIdx.z;
  __shared__ float sBC[2][32][32];
  for (int i = tid; i < 2048; i += 256) {
    const int br = i >> 10, l = (i >> 5) & 31, c = i & 31;
    sBC[br][l][c] = dbc[(size_t)((br * 4 + b) * 1024 + chunk * 32 + l) * 128 + 64 + c];
  }
  __syncthreads();
  float a[16], h0[16], h1[16];
  const size_t cb0 = ((size_t)(b * 32 + chunk) * 32) * 1024 + d;
  const size_t cb1 = ((size_t)((4 + b) * 32 + chunk) * 32) * 1024 + d;
#pragma unroll
  for (int n = 0; n < 16; ++n) {
    a[n] = a_tab[d * 16 + n];
    h0[n] = cs[cb0 + (size_t)n * 1024];
    h1[n] = cs[cb1 + (size_t)n * 1024];
  }
  const float dpv = Dp[d];
  const size_t r0 = (size_t)(b * 1024 + chunk * 32) * 1024 + d;
  const size_t r1 = (size_t)(4096 * 1024) + r0;
  for (int l = 0; l < 32; ++l) {
    const float dlt0 = b2f(delta[r0 + (size_t)l * 1024]);
    const float xv0  = b2f(xc[r0 + (size_t)l * 1024]);
    const float dlt1 = b2f(delta[r1 + (size_t)l * 1024]);
    const float xv1  = b2f(xc[r1 + (size_t)l * 1024]);
    const float dx0 = dlt0 * xv0;
    const float dx1 = dlt1 * xv1;
    float yv = dpv * (xv0 + xv1);
#pragma unroll
    for (int n = 0; n < 16; ++n) {
      h0[n] = fmaf(__expf(dlt0 * a[n]), h0[n], dx0 * sBC[0][l][n]);
      yv = fmaf(h0[n], sBC[0][l][16 + n], yv);
    }
#pragma unroll
    for (int n = 0; n < 16; ++n) {
      h1[n] = fmaf(__expf(dlt1 * a[n]), h1[n], dx1 * sBC[1][l][n]);
      yv = fmaf(h1[n], sBC[1][l][16 + n], yv);
    }
    yb[r0 + (size_t)l * 1024] = f2b(yv);
  }
}

// ---------------------------------------------------------------- launch
extern "C" void kernel_launch(void* const* d_in, const int* in_sizes, int n_in,
                              void* d_out, int out_size, void* d_ws, size_t ws_size,
                              hipStream_t stream) {
  const float* x     = (const float*)d_in[0];
  const float* Wf    = (const float*)d_in[1];
  const float* bf    = (const float*)d_in[2];
  const float* Wb    = (const float*)d_in[3];
  const float* bb    = (const float*)d_in[4];
  const float* ln_w  = (const float*)d_in[5];
  const float* ln_b  = (const float*)d_in[6];
  const float* W_dbc = (const float*)d_in[7];
  const float* W_dt  = (const float*)d_in[8];
  const float* b_dt  = (const float*)d_in[9];
  const float* A_log = (const float*)d_in[10];
  const float* Dp    = (const float*)d_in[11];
  float* out = (float*)d_out;
  char* wsb = (char*)d_ws;

  const size_t MB = 1024 * 1024;
  const size_t M1 = 1048576;
  unsigned short* zTb    = (unsigned short*)(wsb + 0);                    //  8 MB
  unsigned short* xcb    = (unsigned short*)(wsb + 8 * MB);               // 16 MB
  unsigned short* deltab = (unsigned short*)(wsb + 24 * MB);              // 16 MB
  float*          dbc    = (float*)(wsb + 40 * MB);                       //  4 MB
  unsigned short* dbcd   = (unsigned short*)(wsb + 44 * MB);              //  1 MB
  unsigned short* Wfb    = (unsigned short*)(wsb + 45 * MB);              //  8 MB
  unsigned short* Wdbcb  = (unsigned short*)(wsb + 53 * MB);              // .25 MB
  unsigned short* Wdtb   = (unsigned short*)(wsb + 53 * MB + 256 * 1024); // .125 MB
  float*          bias2  = (float*)(wsb + 53 * MB + 384 * 1024);          // 8 KB
  float*          a_tab  = (float*)(wsb + 53 * MB + 448 * 1024);          // 64 KB
  unsigned short* xnb    = (unsigned short*)(wsb + 54 * MB);              //  8 MB
  unsigned short* zb     = (unsigned short*)(wsb + 62 * MB);              //  8 MB
  float*          cs     = (float*)(wsb + 70 * MB);                       // 32 MB
  unsigned short* Asum   = (unsigned short*)(wsb + 102 * MB);             //  8 MB
  // total 110 MB

  // 1) weight prep + LN + z^T
  prep<<<dim3(9032), dim3(256), 0, stream>>>(Wf, Wb, W_dbc, W_dt, bf, bb, A_log,
                                             Wfb, Wdbcb, Wdtb, bias2, a_tab);
  ln_kernel<<<dim3(4096), dim3(256), 0, stream>>>(x, ln_w, ln_b, xnb, zb);
  transpose_bf16<<<dim3(32, 32, 4), dim3(256), 0, stream>>>(zb, zTb);

  // 2) K2: xcb[br] = bf16(xn @ W{f,b}^T + bias)
  gemm_mfma<1, 128, 128><<<dim3(8, 32, 2), dim3(256), 0, stream>>>(
      xnb, Wfb, bias2, nullptr, nullptr, xcb,
      1024, 1024, 1024, 0, 1024, 1024,
      0, M1, 0, 0, 1024, 4 * M1);

  // 3) K3: dbc = xc @ W_dbc^T (f32, N pad 128) ; dbcd = bf16 of delta cols
  gemm_mfma<0, 64, 128><<<dim3(1, 128, 1), dim3(256), 0, stream>>>(
      xcb, Wdbcb, nullptr, nullptr, dbc, dbcd,
      1024, 1024, 1024, 128, 64, 64,
      0, 0, 0, 0, 0, 0);

  // 4) K4: deltab = bf16(softplus(dbc_delta @ W_dt^T + b_dt))
  gemm_mfma<2, 128, 128><<<dim3(8, 64, 1), dim3(256), 0, stream>>>(
      dbcd, Wdtb, b_dt, nullptr, nullptr, deltab,
      64, 64, 64, 0, 1024, 1024,
      0, 0, 0, 0, 0, 0);

  // 5) chunked selective scan (both branches), Asum = y1+y2 bf16
  scan_a<<<dim3(4, 32, 8), dim3(256), 0, stream>>>(deltab, xcb, dbc, a_tab, cs);
  scan_b<<<dim3(16, 4, 8), dim3(256), 0, stream>>>(cs);
  scan_c<<<dim3(4, 32, 4), dim3(256), 0, stream>>>(deltab, xcb, dbc, a_tab, Dp, cs, Asum);

  // 6) K6: out[b] = Asum[b] @ z[b]^T' + x[b]
  gemm_mfma<3, 64, 128><<<dim3(8, 16, 4), dim3(256), 0, stream>>>(
      Asum, zTb, nullptr, x, out, nullptr,
      1024, 1024, 1024, 1024, 0, 0,
      M1, M1, M1, M1, 0, 0);
}

// Round 4
// 185.634 us; speedup vs baseline: 7.4961x; 1.1668x over previous
//
#include <hip/hip_runtime.h>
#include <hip/hip_bf16.h>
#include <cstdint>

typedef __attribute__((ext_vector_type(8))) short bf16x8;
typedef __attribute__((ext_vector_type(4))) float f32x4;

__device__ inline unsigned short f2b(float f) {
  unsigned u = __builtin_bit_cast(unsigned, f);
  u += 0x7fffu + ((u >> 16) & 1u);
  return (unsigned short)(u >> 16);
}
__device__ inline float b2f(unsigned short u) {
  return __builtin_bit_cast(float, (unsigned)u << 16);
}
__device__ inline void gload_lds16(const void* g, void* l) {
  __builtin_amdgcn_global_load_lds((const __attribute__((address_space(1))) void*)g,
                                   (__attribute__((address_space(3))) void*)l, 16, 0, 0);
}
// fast softplus: log1pf is a ~200-instr slow path on ROCm (R3: 470cyc/elem, 25us of VALU)
__device__ inline float softplus_fast(float v) {
  return (v > 15.f) ? v : __logf(1.f + __expf(v));
}

// ---------------------------------------------------------------- LayerNorm -> xn(bf16), z=silu(xn)(bf16)
__global__ __launch_bounds__(256) void ln_kernel(
    const float* __restrict__ x, const float* __restrict__ w,
    const float* __restrict__ b, unsigned short* __restrict__ xnb,
    unsigned short* __restrict__ zb) {
  const int row = blockIdx.x;
  const int tid = threadIdx.x;
  const float4 v = ((const float4*)(x + (size_t)row * 1024))[tid];
  float s  = v.x + v.y + v.z + v.w;
  float ss = v.x * v.x + v.y * v.y + v.z * v.z + v.w * v.w;
#pragma unroll
  for (int o = 32; o > 0; o >>= 1) {
    s  += __shfl_down(s, o);
    ss += __shfl_down(ss, o);
  }
  __shared__ float red[10];
  const int wid = tid >> 6, lane = tid & 63;
  if (lane == 0) { red[wid] = s; red[4 + wid] = ss; }
  __syncthreads();
  if (tid == 0) {
    const float S0 = red[0] + red[1] + red[2] + red[3];
    const float S1 = red[4] + red[5] + red[6] + red[7];
    const float mu = S0 * (1.0f / 1024.0f);
    const float var = S1 * (1.0f / 1024.0f) - mu * mu;
    red[8] = mu;
    red[9] = rsqrtf(var + 1e-5f);
  }
  __syncthreads();
  const float mu = red[8], rs = red[9];
  const float4 wv = ((const float4*)w)[tid];
  const float4 bv = ((const float4*)b)[tid];
  float o0 = (v.x - mu) * rs * wv.x + bv.x;
  float o1 = (v.y - mu) * rs * wv.y + bv.y;
  float o2 = (v.z - mu) * rs * wv.z + bv.z;
  float o3 = (v.w - mu) * rs * wv.w + bv.w;
  ushort4 xo, zo;
  xo.x = f2b(o0); xo.y = f2b(o1); xo.z = f2b(o2); xo.w = f2b(o3);
  zo.x = f2b(o0 / (1.0f + __expf(-o0)));
  zo.y = f2b(o1 / (1.0f + __expf(-o1)));
  zo.z = f2b(o2 / (1.0f + __expf(-o2)));
  zo.w = f2b(o3 / (1.0f + __expf(-o3)));
  ((ushort4*)(xnb + (size_t)row * 1024))[tid] = xo;
  ((ushort4*)(zb + (size_t)row * 1024))[tid] = zo;
}

// ---------------------------------------------------------------- bf16 transpose per batch (z -> z^T)
__global__ __launch_bounds__(256) void transpose_bf16(
    const unsigned short* __restrict__ in, unsigned short* __restrict__ out) {
  __shared__ unsigned short t[32][33];
  const int tid = threadIdx.x;
  const int d0 = blockIdx.x * 32, s0 = blockIdx.y * 32;
  const size_t bb = (size_t)blockIdx.z * 1024 * 1024;
  const int lr = tid >> 3, lq = (tid & 7) * 4;
  const ushort4 v = *(const ushort4*)&in[bb + (size_t)(s0 + lr) * 1024 + d0 + lq];
  t[lr][lq + 0] = v.x; t[lr][lq + 1] = v.y; t[lr][lq + 2] = v.z; t[lr][lq + 3] = v.w;
  __syncthreads();
  ushort4 o;
  o.x = t[lq + 0][lr]; o.y = t[lq + 1][lr]; o.z = t[lq + 2][lr]; o.w = t[lq + 3][lr];
  *(ushort4*)&out[bb + (size_t)(d0 + lr) * 1024 + s0 + lq] = o;
}

// ---------------------------------------------------------------- fused weight prep
__global__ void prep(const float* __restrict__ Wf, const float* __restrict__ Wb,
                     const float* __restrict__ W_dbc, const float* __restrict__ W_dt,
                     const float* __restrict__ bf_, const float* __restrict__ bb_,
                     const float* __restrict__ A_log,
                     unsigned short* __restrict__ Wfb, unsigned short* __restrict__ Wdbcb,
                     unsigned short* __restrict__ Wdtb, float* __restrict__ bias2,
                     float* __restrict__ a_tab) {
  const int i = blockIdx.x * 256 + threadIdx.x;
  if (i < 1048576) {
    Wfb[i] = f2b(Wf[i]);
  } else if (i < 2097152) {
    Wfb[i] = f2b(Wb[i - 1048576]);
  } else if (i < 2228224) {
    const int j = i - 2097152;
    Wdbcb[j] = (j < 98304) ? f2b(W_dbc[j]) : (unsigned short)0;
  } else if (i < 2293760) {
    const int j = i - 2228224;
    Wdtb[j] = f2b(W_dt[j]);
  } else if (i < 2295808) {
    const int j = i - 2293760;
    bias2[j] = (j < 1024) ? bf_[j] : bb_[j - 1024];
  } else if (i < 2312192) {
    const int j = i - 2295808;
    a_tab[j] = -__expf(A_log[j]);
  }
}

// ---------------------------------------------------------------- bf16 MFMA GEMM: C = A @ B^T (+epilogue)
// EPI: 0 none, 1 +bias[col], 2 softplus(acc+bias[col]), 3 +Cadd[row][col]
template <int EPI, int BM, int BN>
__global__ __launch_bounds__(256) void gemm_mfma(
    const unsigned short* __restrict__ A, const unsigned short* __restrict__ B,
    const float* __restrict__ bias, const float* __restrict__ Cadd,
    float* __restrict__ C, unsigned short* __restrict__ C2,
    int K, int lda, int ldb, int ldc, int ldc2, int n2,
    size_t astride, size_t bstride, size_t cstride, size_t addstride,
    size_t biasstride, size_t c2stride) {
  constexpr int WTM = BM / 32;
  constexpr int WTN = BN / 32;
  __shared__ unsigned short As[BM * 32];
  __shared__ unsigned short Bs[BN * 32];
  const int tid = threadIdx.x;
  const int lane = tid & 63;
  const int wid = tid >> 6;
  const int wm = wid >> 1, wn = wid & 1;
  const int mbase = blockIdx.y * BM;
  const int nbase = blockIdx.x * BN;
  const size_t zz = blockIdx.z;
  A += zz * astride;
  B += zz * bstride;
  if (C) C += zz * cstride;
  if (EPI == 3) Cadd += zz * addstride;
  if (EPI == 1 || EPI == 2) bias += zz * biasstride;
  if (C2) C2 += zz * c2stride;

  f32x4 acc[WTM][WTN];
#pragma unroll
  for (int i = 0; i < WTM; ++i)
#pragma unroll
    for (int j = 0; j < WTN; ++j) acc[i][j] = (f32x4){0.f, 0.f, 0.f, 0.f};

  const int r0 = tid >> 2;
  const int ch0 = (tid & 3) * 8;

  for (int kt = 0; kt < K; kt += 32) {
#pragma unroll
    for (int i = 0; i < BM / 64; ++i)
      gload_lds16(A + (size_t)(mbase + r0 + i * 64) * lda + kt + ch0,
                  &As[((size_t)tid + i * 256) * 8]);
#pragma unroll
    for (int i = 0; i < BN / 64; ++i)
      gload_lds16(B + (size_t)(nbase + r0 + i * 64) * ldb + kt + ch0,
                  &Bs[((size_t)tid + i * 256) * 8]);
    __syncthreads();
    const int arow = wm * (BM / 2) + (lane & 15);
    const int brow = wn * (BN / 2) + (lane & 15);
    const int kofs = (lane >> 4) * 8;
    bf16x8 af[WTM], bfr[WTN];
#pragma unroll
    for (int mi = 0; mi < WTM; ++mi) af[mi] = *(const bf16x8*)&As[(size_t)(arow + mi * 16) * 32 + kofs];
#pragma unroll
    for (int ni = 0; ni < WTN; ++ni) bfr[ni] = *(const bf16x8*)&Bs[(size_t)(brow + ni * 16) * 32 + kofs];
#pragma unroll
    for (int mi = 0; mi < WTM; ++mi)
#pragma unroll
      for (int ni = 0; ni < WTN; ++ni)
        acc[mi][ni] = __builtin_amdgcn_mfma_f32_16x16x32_bf16(af[mi], bfr[ni], acc[mi][ni], 0, 0, 0);
    __syncthreads();
  }

  const int lrow = (lane >> 4) * 4, lcol = lane & 15;
#pragma unroll
  for (int mi = 0; mi < WTM; ++mi) {
#pragma unroll
    for (int ni = 0; ni < WTN; ++ni) {
      const int col = nbase + wn * (BN / 2) + ni * 16 + lcol;
      const int row0 = mbase + wm * (BM / 2) + mi * 16 + lrow;
#pragma unroll
      for (int r = 0; r < 4; ++r) {
        float v = acc[mi][ni][r];
        const int row = row0 + r;
        if (EPI == 1) v += bias[col];
        if (EPI == 2) {
          v += bias[col];
          v = softplus_fast(v);
        }
        if (EPI == 3) v += Cadd[(size_t)row * ldc + col];
        if (C) C[(size_t)row * ldc + col] = v;
        if (C2 && col < n2) C2[(size_t)row * ldc2 + col] = f2b(v);
      }
    }
  }
}

// ---------------------------------------------------------------- scan pass A
__global__ __launch_bounds__(256) void scan_a(
    const unsigned short* __restrict__ delta, const unsigned short* __restrict__ xc,
    const float* __restrict__ dbc, const float* __restrict__ a_tab,
    float* __restrict__ cs) {
  const int tid = threadIdx.x;
  const int d = blockIdx.x * 256 + tid;
  const int chunk = blockIdx.y;
  const int z = blockIdx.z;
  __shared__ float sB[32][16];
  for (int i = tid; i < 512; i += 256) {
    const int l = i >> 4, n = i & 15;
    sB[l][n] = dbc[(size_t)(z * 1024 + chunk * 32 + l) * 128 + 64 + n];
  }
  __syncthreads();
  float a[16], h[16];
#pragma unroll
  for (int n = 0; n < 16; ++n) {
    a[n] = a_tab[d * 16 + n];
    h[n] = 0.0f;
  }
  float sdlt = 0.0f;
  const size_t rbase = (size_t)(z * 1024 + chunk * 32) * 1024 + d;
  for (int l = 0; l < 32; ++l) {
    const float dlt = b2f(delta[rbase + (size_t)l * 1024]);
    const float xv  = b2f(xc[rbase + (size_t)l * 1024]);
    const float dx = dlt * xv;
    sdlt += dlt;
#pragma unroll
    for (int n = 0; n < 16; ++n)
      h[n] = fmaf(__expf(dlt * a[n]), h[n], dx * sB[l][n]);
  }
  const size_t cbase = ((size_t)(z * 32 + chunk) * 32) * 1024 + d;
#pragma unroll
  for (int n = 0; n < 16; ++n) {
    cs[cbase + (size_t)n * 1024] = __expf(a[n] * sdlt);
    cs[cbase + (size_t)(16 + n) * 1024] = h[n];
  }
}

// ---------------------------------------------------------------- scan pass B
__global__ __launch_bounds__(256) void scan_b(float* __restrict__ cs) {
  const int tid = threadIdx.x;
  const int d = blockIdx.x * 64 + (tid & 63);
  const int n = blockIdx.y * 4 + (tid >> 6);
  const int z = blockIdx.z;
  float h = 0.0f;
  for (int c = 0; c < 32; ++c) {
    const size_t base = ((size_t)(z * 32 + c) * 32) * 1024 + d;
    const float Ap = cs[base + (size_t)n * 1024];
    const float he = cs[base + (size_t)(16 + n) * 1024];
    cs[base + (size_t)n * 1024] = h;
    h = fmaf(Ap, h, he);
  }
}

// ---------------------------------------------------------------- scan pass C (both branches fused)
__global__ __launch_bounds__(256) void scan_c(
    const unsigned short* __restrict__ delta, const unsigned short* __restrict__ xc,
    const float* __restrict__ dbc, const float* __restrict__ a_tab,
    const float* __restrict__ Dp, const float* __restrict__ cs,
    unsigned short* __restrict__ yb) {
  const int tid = threadIdx.x;
  const int d = blockIdx.x * 256 + tid;
  const int chunk = blockIdx.y;
  const int b = blockIdx.z;
  __shared__ float sBC[2][32][32];
  for (int i = tid; i < 2048; i += 256) {
    const int br = i >> 10, l = (i >> 5) & 31, c = i & 31;
    sBC[br][l][c] = dbc[(size_t)((br * 4 + b) * 1024 + chunk * 32 + l) * 128 + 64 + c];
  }
  __syncthreads();
  float a[16], h0[16], h1[16];
  const size_t cb0 = ((size_t)(b * 32 + chunk) * 32) * 1024 + d;
  const size_t cb1 = ((size_t)((4 + b) * 32 + chunk) * 32) * 1024 + d;
#pragma unroll
  for (int n = 0; n < 16; ++n) {
    a[n] = a_tab[d * 16 + n];
    h0[n] = cs[cb0 + (size_t)n * 1024];
    h1[n] = cs[cb1 + (size_t)n * 1024];
  }
  const float dpv = Dp[d];
  const size_t r0 = (size_t)(b * 1024 + chunk * 32) * 1024 + d;
  const size_t r1 = (size_t)(4096 * 1024) + r0;
  for (int l = 0; l < 32; ++l) {
    const float dlt0 = b2f(delta[r0 + (size_t)l * 1024]);
    const float xv0  = b2f(xc[r0 + (size_t)l * 1024]);
    const float dlt1 = b2f(delta[r1 + (size_t)l * 1024]);
    const float xv1  = b2f(xc[r1 + (size_t)l * 1024]);
    const float dx0 = dlt0 * xv0;
    const float dx1 = dlt1 * xv1;
    float yv = dpv * (xv0 + xv1);
#pragma unroll
    for (int n = 0; n < 16; ++n) {
      h0[n] = fmaf(__expf(dlt0 * a[n]), h0[n], dx0 * sBC[0][l][n]);
      yv = fmaf(h0[n], sBC[0][l][16 + n], yv);
    }
#pragma unroll
    for (int n = 0; n < 16; ++n) {
      h1[n] = fmaf(__expf(dlt1 * a[n]), h1[n], dx1 * sBC[1][l][n]);
      yv = fmaf(h1[n], sBC[1][l][16 + n], yv);
    }
    yb[r0 + (size_t)l * 1024] = f2b(yv);
  }
}

// ---------------------------------------------------------------- launch
extern "C" void kernel_launch(void* const* d_in, const int* in_sizes, int n_in,
                              void* d_out, int out_size, void* d_ws, size_t ws_size,
                              hipStream_t stream) {
  const float* x     = (const float*)d_in[0];
  const float* Wf    = (const float*)d_in[1];
  const float* bf    = (const float*)d_in[2];
  const float* Wb    = (const float*)d_in[3];
  const float* bb    = (const float*)d_in[4];
  const float* ln_w  = (const float*)d_in[5];
  const float* ln_b  = (const float*)d_in[6];
  const float* W_dbc = (const float*)d_in[7];
  const float* W_dt  = (const float*)d_in[8];
  const float* b_dt  = (const float*)d_in[9];
  const float* A_log = (const float*)d_in[10];
  const float* Dp    = (const float*)d_in[11];
  float* out = (float*)d_out;
  char* wsb = (char*)d_ws;

  const size_t MB = 1024 * 1024;
  const size_t M1 = 1048576;
  unsigned short* zTb    = (unsigned short*)(wsb + 0);                    //  8 MB
  unsigned short* xcb    = (unsigned short*)(wsb + 8 * MB);               // 16 MB
  unsigned short* deltab = (unsigned short*)(wsb + 24 * MB);              // 16 MB
  float*          dbc    = (float*)(wsb + 40 * MB);                       //  4 MB
  unsigned short* dbcd   = (unsigned short*)(wsb + 44 * MB);              //  1 MB
  unsigned short* Wfb    = (unsigned short*)(wsb + 45 * MB);              //  8 MB
  unsigned short* Wdbcb  = (unsigned short*)(wsb + 53 * MB);              // .25 MB
  unsigned short* Wdtb   = (unsigned short*)(wsb + 53 * MB + 256 * 1024); // .125 MB
  float*          bias2  = (float*)(wsb + 53 * MB + 384 * 1024);          // 8 KB
  float*          a_tab  = (float*)(wsb + 53 * MB + 448 * 1024);          // 64 KB
  unsigned short* xnb    = (unsigned short*)(wsb + 54 * MB);              //  8 MB
  unsigned short* zb     = (unsigned short*)(wsb + 62 * MB);              //  8 MB
  float*          cs     = (float*)(wsb + 70 * MB);                       // 32 MB
  unsigned short* Asum   = (unsigned short*)(wsb + 102 * MB);             //  8 MB

  // 1) weight prep + LN + z^T
  prep<<<dim3(9032), dim3(256), 0, stream>>>(Wf, Wb, W_dbc, W_dt, bf, bb, A_log,
                                             Wfb, Wdbcb, Wdtb, bias2, a_tab);
  ln_kernel<<<dim3(4096), dim3(256), 0, stream>>>(x, ln_w, ln_b, xnb, zb);
  transpose_bf16<<<dim3(32, 32, 4), dim3(256), 0, stream>>>(zb, zTb);

  // 2) K2: xcb[br] = bf16(xn @ W{f,b}^T + bias)  -- BM=64: 1024 blocks (4/CU)
  gemm_mfma<1, 64, 128><<<dim3(8, 64, 2), dim3(256), 0, stream>>>(
      xnb, Wfb, bias2, nullptr, nullptr, xcb,
      1024, 1024, 1024, 0, 1024, 1024,
      0, M1, 0, 0, 1024, 4 * M1);

  // 3) K3: dbc = xc @ W_dbc^T (f32, N pad 128) ; dbcd = bf16 of delta cols
  gemm_mfma<0, 64, 128><<<dim3(1, 128, 1), dim3(256), 0, stream>>>(
      xcb, Wdbcb, nullptr, nullptr, dbc, dbcd,
      1024, 1024, 1024, 128, 64, 64,
      0, 0, 0, 0, 0, 0);

  // 4) K4: deltab = bf16(softplus(dbc_delta @ W_dt^T + b_dt))  -- fast softplus
  gemm_mfma<2, 128, 128><<<dim3(8, 64, 1), dim3(256), 0, stream>>>(
      dbcd, Wdtb, b_dt, nullptr, nullptr, deltab,
      64, 64, 64, 0, 1024, 1024,
      0, 0, 0, 0, 0, 0);

  // 5) chunked selective scan (both branches), Asum = y1+y2 bf16
  scan_a<<<dim3(4, 32, 8), dim3(256), 0, stream>>>(deltab, xcb, dbc, a_tab, cs);
  scan_b<<<dim3(16, 4, 8), dim3(256), 0, stream>>>(cs);
  scan_c<<<dim3(4, 32, 4), dim3(256), 0, stream>>>(deltab, xcb, dbc, a_tab, Dp, cs, Asum);

  // 6) K6: out[b] = Asum[b] @ zT[b] + x[b]  -- 64x64 tiles: 1024 blocks (4/CU)
  gemm_mfma<3, 64, 64><<<dim3(16, 16, 4), dim3(256), 0, stream>>>(
      Asum, zTb, nullptr, x, out, nullptr,
      1024, 1024, 1024, 1024, 0, 0,
      M1, M1, M1, M1, 0, 0);
}

// Round 5
// 179.836 us; speedup vs baseline: 7.7378x; 1.0322x over previous
//
#include <hip/hip_runtime.h>
#include <hip/hip_bf16.h>
#include <cstdint>

typedef __attribute__((ext_vector_type(8))) short bf16x8;
typedef __attribute__((ext_vector_type(4))) float f32x4;

__device__ inline unsigned short f2b(float f) {
  unsigned u = __builtin_bit_cast(unsigned, f);
  u += 0x7fffu + ((u >> 16) & 1u);
  return (unsigned short)(u >> 16);
}
__device__ inline float b2f(unsigned short u) {
  return __builtin_bit_cast(float, (unsigned)u << 16);
}
__device__ inline void gload_lds16(const void* g, void* l) {
  __builtin_amdgcn_global_load_lds((const __attribute__((address_space(1))) void*)g,
                                   (__attribute__((address_space(3))) void*)l, 16, 0, 0);
}
// fast softplus: log1pf is a ~200-instr slow path on ROCm (R3: 470cyc/elem)
__device__ inline float softplus_fast(float v) {
  return (v > 15.f) ? v : __logf(1.f + __expf(v));
}

// ---------------------------------------------------------------- LayerNorm -> xn(bf16), z=silu(xn)(bf16)
__global__ __launch_bounds__(256) void ln_kernel(
    const float* __restrict__ x, const float* __restrict__ w,
    const float* __restrict__ b, unsigned short* __restrict__ xnb,
    unsigned short* __restrict__ zb) {
  const int row = blockIdx.x;
  const int tid = threadIdx.x;
  const float4 v = ((const float4*)(x + (size_t)row * 1024))[tid];
  float s  = v.x + v.y + v.z + v.w;
  float ss = v.x * v.x + v.y * v.y + v.z * v.z + v.w * v.w;
#pragma unroll
  for (int o = 32; o > 0; o >>= 1) {
    s  += __shfl_down(s, o);
    ss += __shfl_down(ss, o);
  }
  __shared__ float red[10];
  const int wid = tid >> 6, lane = tid & 63;
  if (lane == 0) { red[wid] = s; red[4 + wid] = ss; }
  __syncthreads();
  if (tid == 0) {
    const float S0 = red[0] + red[1] + red[2] + red[3];
    const float S1 = red[4] + red[5] + red[6] + red[7];
    const float mu = S0 * (1.0f / 1024.0f);
    const float var = S1 * (1.0f / 1024.0f) - mu * mu;
    red[8] = mu;
    red[9] = rsqrtf(var + 1e-5f);
  }
  __syncthreads();
  const float mu = red[8], rs = red[9];
  const float4 wv = ((const float4*)w)[tid];
  const float4 bv = ((const float4*)b)[tid];
  float o0 = (v.x - mu) * rs * wv.x + bv.x;
  float o1 = (v.y - mu) * rs * wv.y + bv.y;
  float o2 = (v.z - mu) * rs * wv.z + bv.z;
  float o3 = (v.w - mu) * rs * wv.w + bv.w;
  ushort4 xo, zo;
  xo.x = f2b(o0); xo.y = f2b(o1); xo.z = f2b(o2); xo.w = f2b(o3);
  zo.x = f2b(o0 / (1.0f + __expf(-o0)));
  zo.y = f2b(o1 / (1.0f + __expf(-o1)));
  zo.z = f2b(o2 / (1.0f + __expf(-o2)));
  zo.w = f2b(o3 / (1.0f + __expf(-o3)));
  ((ushort4*)(xnb + (size_t)row * 1024))[tid] = xo;
  ((ushort4*)(zb + (size_t)row * 1024))[tid] = zo;
}

// ---------------------------------------------------------------- bf16 transpose per batch (z -> z^T)
__global__ __launch_bounds__(256) void transpose_bf16(
    const unsigned short* __restrict__ in, unsigned short* __restrict__ out) {
  __shared__ unsigned short t[32][33];
  const int tid = threadIdx.x;
  const int d0 = blockIdx.x * 32, s0 = blockIdx.y * 32;
  const size_t bb = (size_t)blockIdx.z * 1024 * 1024;
  const int lr = tid >> 3, lq = (tid & 7) * 4;
  const ushort4 v = *(const ushort4*)&in[bb + (size_t)(s0 + lr) * 1024 + d0 + lq];
  t[lr][lq + 0] = v.x; t[lr][lq + 1] = v.y; t[lr][lq + 2] = v.z; t[lr][lq + 3] = v.w;
  __syncthreads();
  ushort4 o;
  o.x = t[lq + 0][lr]; o.y = t[lq + 1][lr]; o.z = t[lq + 2][lr]; o.w = t[lq + 3][lr];
  *(ushort4*)&out[bb + (size_t)(d0 + lr) * 1024 + s0 + lq] = o;
}

// ---------------------------------------------------------------- fused weight prep
// a_tab = -exp(A_log) * log2(e)   (consumed via exp2)
__global__ void prep(const float* __restrict__ Wf, const float* __restrict__ Wb,
                     const float* __restrict__ W_dbc, const float* __restrict__ W_dt,
                     const float* __restrict__ bf_, const float* __restrict__ bb_,
                     const float* __restrict__ A_log,
                     unsigned short* __restrict__ Wfb, unsigned short* __restrict__ Wdbcb,
                     unsigned short* __restrict__ Wdtb, float* __restrict__ bias2,
                     float* __restrict__ a_tab) {
  const int i = blockIdx.x * 256 + threadIdx.x;
  if (i < 1048576) {
    Wfb[i] = f2b(Wf[i]);
  } else if (i < 2097152) {
    Wfb[i] = f2b(Wb[i - 1048576]);
  } else if (i < 2228224) {
    const int j = i - 2097152;
    Wdbcb[j] = (j < 98304) ? f2b(W_dbc[j]) : (unsigned short)0;
  } else if (i < 2293760) {
    const int j = i - 2228224;
    Wdtb[j] = f2b(W_dt[j]);
  } else if (i < 2295808) {
    const int j = i - 2293760;
    bias2[j] = (j < 1024) ? bf_[j] : bb_[j - 1024];
  } else if (i < 2312192) {
    const int j = i - 2295808;
    a_tab[j] = -__expf(A_log[j]) * 1.4426950408889634f;
  }
}

// ---------------------------------------------------------------- bf16 MFMA GEMM: C = A @ B^T (+epilogue)
// EPI: 0 none, 1 +bias[col], 2 softplus(acc+bias[col]), 3 +Cadd[row][col]
template <int EPI, int BM, int BN>
__global__ __launch_bounds__(256) void gemm_mfma(
    const unsigned short* __restrict__ A, const unsigned short* __restrict__ B,
    const float* __restrict__ bias, const float* __restrict__ Cadd,
    float* __restrict__ C, unsigned short* __restrict__ C2,
    int K, int lda, int ldb, int ldc, int ldc2, int n2,
    size_t astride, size_t bstride, size_t cstride, size_t addstride,
    size_t biasstride, size_t c2stride) {
  constexpr int WTM = BM / 32;
  constexpr int WTN = BN / 32;
  __shared__ unsigned short As[BM * 32];
  __shared__ unsigned short Bs[BN * 32];
  const int tid = threadIdx.x;
  const int lane = tid & 63;
  const int wid = tid >> 6;
  const int wm = wid >> 1, wn = wid & 1;
  const int mbase = blockIdx.y * BM;
  const int nbase = blockIdx.x * BN;
  const size_t zz = blockIdx.z;
  A += zz * astride;
  B += zz * bstride;
  if (C) C += zz * cstride;
  if (EPI == 3) Cadd += zz * addstride;
  if (EPI == 1 || EPI == 2) bias += zz * biasstride;
  if (C2) C2 += zz * c2stride;

  f32x4 acc[WTM][WTN];
#pragma unroll
  for (int i = 0; i < WTM; ++i)
#pragma unroll
    for (int j = 0; j < WTN; ++j) acc[i][j] = (f32x4){0.f, 0.f, 0.f, 0.f};

  const int r0 = tid >> 2;
  const int ch0 = (tid & 3) * 8;

  for (int kt = 0; kt < K; kt += 32) {
#pragma unroll
    for (int i = 0; i < BM / 64; ++i)
      gload_lds16(A + (size_t)(mbase + r0 + i * 64) * lda + kt + ch0,
                  &As[((size_t)tid + i * 256) * 8]);
#pragma unroll
    for (int i = 0; i < BN / 64; ++i)
      gload_lds16(B + (size_t)(nbase + r0 + i * 64) * ldb + kt + ch0,
                  &Bs[((size_t)tid + i * 256) * 8]);
    __syncthreads();
    const int arow = wm * (BM / 2) + (lane & 15);
    const int brow = wn * (BN / 2) + (lane & 15);
    const int kofs = (lane >> 4) * 8;
    bf16x8 af[WTM], bfr[WTN];
#pragma unroll
    for (int mi = 0; mi < WTM; ++mi) af[mi] = *(const bf16x8*)&As[(size_t)(arow + mi * 16) * 32 + kofs];
#pragma unroll
    for (int ni = 0; ni < WTN; ++ni) bfr[ni] = *(const bf16x8*)&Bs[(size_t)(brow + ni * 16) * 32 + kofs];
#pragma unroll
    for (int mi = 0; mi < WTM; ++mi)
#pragma unroll
      for (int ni = 0; ni < WTN; ++ni)
        acc[mi][ni] = __builtin_amdgcn_mfma_f32_16x16x32_bf16(af[mi], bfr[ni], acc[mi][ni], 0, 0, 0);
    __syncthreads();
  }

  const int lrow = (lane >> 4) * 4, lcol = lane & 15;
#pragma unroll
  for (int mi = 0; mi < WTM; ++mi) {
#pragma unroll
    for (int ni = 0; ni < WTN; ++ni) {
      const int col = nbase + wn * (BN / 2) + ni * 16 + lcol;
      const int row0 = mbase + wm * (BM / 2) + mi * 16 + lrow;
#pragma unroll
      for (int r = 0; r < 4; ++r) {
        float v = acc[mi][ni][r];
        const int row = row0 + r;
        if (EPI == 1) v += bias[col];
        if (EPI == 2) {
          v += bias[col];
          v = softplus_fast(v);
        }
        if (EPI == 3) v += Cadd[(size_t)row * ldc + col];
        if (C) C[(size_t)row * ldc + col] = v;
        if (C2 && col < n2) C2[(size_t)row * ldc2 + col] = f2b(v);
      }
    }
  }
}

// ================================================================ chunked scan
// 64 chunks x 16 steps. cs layout: [z=8][chunk=64][slot=32][d=1024]
//   slot n      = chunk decay Ap (pass A) -> h_start (pass B, in place)
//   slot 16+n   = chunk-local end state h_end

// ---------------------------------------------------------------- scan pass A
__global__ __launch_bounds__(256) void scan_a(
    const unsigned short* __restrict__ delta, const unsigned short* __restrict__ xc,
    const float* __restrict__ dbc, const float* __restrict__ a_tab,
    float* __restrict__ cs) {
  const int tid = threadIdx.x;
  const int d = blockIdx.x * 256 + tid;
  const int chunk = blockIdx.y;
  const int z = blockIdx.z;
  __shared__ float sB[16][16];
  {
    const int l = tid >> 4, n = tid & 15;
    sB[l][n] = dbc[(size_t)(z * 1024 + chunk * 16 + l) * 128 + 64 + n];
  }
  __syncthreads();
  float a[16], h[16];
#pragma unroll
  for (int n = 0; n < 16; ++n) {
    a[n] = a_tab[d * 16 + n];
    h[n] = 0.0f;
  }
  float sdlt = 0.0f;
  const size_t rbase = (size_t)(z * 1024 + chunk * 16) * 1024 + d;
  for (int l = 0; l < 16; ++l) {
    const float dlt = b2f(delta[rbase + (size_t)l * 1024]);
    const float xv  = b2f(xc[rbase + (size_t)l * 1024]);
    const float dx = dlt * xv;
    sdlt += dlt;
#pragma unroll
    for (int n = 0; n < 16; ++n)
      h[n] = fmaf(__builtin_amdgcn_exp2f(dlt * a[n]), h[n], dx * sB[l][n]);
  }
  const size_t cbase = ((size_t)(z * 64 + chunk) * 32) * 1024 + d;
#pragma unroll
  for (int n = 0; n < 16; ++n) {
    cs[cbase + (size_t)n * 1024] = __builtin_amdgcn_exp2f(a[n] * sdlt);
    cs[cbase + (size_t)(16 + n) * 1024] = h[n];
  }
}

// ---------------------------------------------------------------- scan pass B (in-place, prefetch ahead of store)
__global__ __launch_bounds__(256) void scan_b(float* __restrict__ cs) {
  const int tid = threadIdx.x;
  const int d = blockIdx.x * 64 + (tid & 63);
  const int n = blockIdx.y * 4 + (tid >> 6);
  const int z = blockIdx.z;
  const size_t cstride = 32 * 1024;
  size_t base = ((size_t)(z * 64) * 32) * 1024 + (size_t)n * 1024 + d;
  float h = 0.0f;
  float Ap = cs[base], he = cs[base + 16 * 1024];
  for (int c = 0; c < 64; ++c) {
    float Ap2 = 0.f, he2 = 0.f;
    if (c < 63) {  // issue next-chunk loads BEFORE the aliasing store
      Ap2 = cs[base + cstride];
      he2 = cs[base + cstride + 16 * 1024];
    }
    cs[base] = h;
    h = fmaf(Ap, h, he);
    Ap = Ap2; he = he2; base += cstride;
  }
}

// ---------------------------------------------------------------- scan pass C (both branches fused)
__global__ __launch_bounds__(256) void scan_c(
    const unsigned short* __restrict__ delta, const unsigned short* __restrict__ xc,
    const float* __restrict__ dbc, const float* __restrict__ a_tab,
    const float* __restrict__ Dp, const float* __restrict__ cs,
    unsigned short* __restrict__ yb) {
  const int tid = threadIdx.x;
  const int d = blockIdx.x * 256 + tid;
  const int chunk = blockIdx.y;
  const int b = blockIdx.z;
  __shared__ float sBC[2][16][32];
  for (int i = tid; i < 1024; i += 256) {
    const int br = i >> 9, l = (i >> 5) & 15, c = i & 31;
    sBC[br][l][c] = dbc[(size_t)((br * 4 + b) * 1024 + chunk * 16 + l) * 128 + 64 + c];
  }
  __syncthreads();
  float a[16], h0[16], h1[16];
  const size_t cb0 = ((size_t)(b * 64 + chunk) * 32) * 1024 + d;
  const size_t cb1 = ((size_t)((4 + b) * 64 + chunk) * 32) * 1024 + d;
#pragma unroll
  for (int n = 0; n < 16; ++n) {
    a[n] = a_tab[d * 16 + n];
    h0[n] = cs[cb0 + (size_t)n * 1024];
    h1[n] = cs[cb1 + (size_t)n * 1024];
  }
  const float dpv = Dp[d];
  const size_t r0 = (size_t)(b * 1024 + chunk * 16) * 1024 + d;
  const size_t r1 = (size_t)(4096 * 1024) + r0;
  for (int l = 0; l < 16; ++l) {
    const float dlt0 = b2f(delta[r0 + (size_t)l * 1024]);
    const float xv0  = b2f(xc[r0 + (size_t)l * 1024]);
    const float dlt1 = b2f(delta[r1 + (size_t)l * 1024]);
    const float xv1  = b2f(xc[r1 + (size_t)l * 1024]);
    const float dx0 = dlt0 * xv0;
    const float dx1 = dlt1 * xv1;
    float yv = dpv * (xv0 + xv1);
#pragma unroll
    for (int n = 0; n < 16; ++n) {
      h0[n] = fmaf(__builtin_amdgcn_exp2f(dlt0 * a[n]), h0[n], dx0 * sBC[0][l][n]);
      yv = fmaf(h0[n], sBC[0][l][16 + n], yv);
    }
#pragma unroll
    for (int n = 0; n < 16; ++n) {
      h1[n] = fmaf(__builtin_amdgcn_exp2f(dlt1 * a[n]), h1[n], dx1 * sBC[1][l][n]);
      yv = fmaf(h1[n], sBC[1][l][16 + n], yv);
    }
    yb[r0 + (size_t)l * 1024] = f2b(yv);
  }
}

// ---------------------------------------------------------------- launch
extern "C" void kernel_launch(void* const* d_in, const int* in_sizes, int n_in,
                              void* d_out, int out_size, void* d_ws, size_t ws_size,
                              hipStream_t stream) {
  const float* x     = (const float*)d_in[0];
  const float* Wf    = (const float*)d_in[1];
  const float* bf    = (const float*)d_in[2];
  const float* Wb    = (const float*)d_in[3];
  const float* bb    = (const float*)d_in[4];
  const float* ln_w  = (const float*)d_in[5];
  const float* ln_b  = (const float*)d_in[6];
  const float* W_dbc = (const float*)d_in[7];
  const float* W_dt  = (const float*)d_in[8];
  const float* b_dt  = (const float*)d_in[9];
  const float* A_log = (const float*)d_in[10];
  const float* Dp    = (const float*)d_in[11];
  float* out = (float*)d_out;
  char* wsb = (char*)d_ws;

  const size_t MB = 1024 * 1024;
  const size_t M1 = 1048576;
  unsigned short* zTb    = (unsigned short*)(wsb + 0);                    //  8 MB
  unsigned short* xcb    = (unsigned short*)(wsb + 8 * MB);               // 16 MB
  unsigned short* deltab = (unsigned short*)(wsb + 24 * MB);              // 16 MB
  float*          dbc    = (float*)(wsb + 40 * MB);                       //  4 MB
  unsigned short* dbcd   = (unsigned short*)(wsb + 44 * MB);              //  1 MB
  unsigned short* Wfb    = (unsigned short*)(wsb + 45 * MB);              //  8 MB
  unsigned short* Wdbcb  = (unsigned short*)(wsb + 53 * MB);              // .25 MB
  unsigned short* Wdtb   = (unsigned short*)(wsb + 53 * MB + 256 * 1024); // .125 MB
  float*          bias2  = (float*)(wsb + 53 * MB + 384 * 1024);          // 8 KB
  float*          a_tab  = (float*)(wsb + 53 * MB + 448 * 1024);          // 64 KB
  unsigned short* xnb    = (unsigned short*)(wsb + 54 * MB);              //  8 MB
  unsigned short* zb     = (unsigned short*)(wsb + 62 * MB);              //  8 MB
  float*          cs     = (float*)(wsb + 70 * MB);                       // 64 MB
  unsigned short* Asum   = (unsigned short*)(wsb + 134 * MB);             //  8 MB
  // total 142 MB (ws poison fill showed 256 MiB available)

  // 1) weight prep + LN + z^T
  prep<<<dim3(9032), dim3(256), 0, stream>>>(Wf, Wb, W_dbc, W_dt, bf, bb, A_log,
                                             Wfb, Wdbcb, Wdtb, bias2, a_tab);
  ln_kernel<<<dim3(4096), dim3(256), 0, stream>>>(x, ln_w, ln_b, xnb, zb);
  transpose_bf16<<<dim3(32, 32, 4), dim3(256), 0, stream>>>(zb, zTb);

  // 2) K2: xcb[br] = bf16(xn @ W{f,b}^T + bias)
  gemm_mfma<1, 64, 128><<<dim3(8, 64, 2), dim3(256), 0, stream>>>(
      xnb, Wfb, bias2, nullptr, nullptr, xcb,
      1024, 1024, 1024, 0, 1024, 1024,
      0, M1, 0, 0, 1024, 4 * M1);

  // 3) K3: dbc = xc @ W_dbc^T (f32, N pad 128, BN=64 -> 256 blocks)
  gemm_mfma<0, 64, 64><<<dim3(2, 128, 1), dim3(256), 0, stream>>>(
      xcb, Wdbcb, nullptr, nullptr, dbc, dbcd,
      1024, 1024, 1024, 128, 64, 64,
      0, 0, 0, 0, 0, 0);

  // 4) K4: deltab = bf16(softplus(dbc_delta @ W_dt^T + b_dt))
  gemm_mfma<2, 128, 128><<<dim3(8, 64, 1), dim3(256), 0, stream>>>(
      dbcd, Wdtb, b_dt, nullptr, nullptr, deltab,
      64, 64, 64, 0, 1024, 1024,
      0, 0, 0, 0, 0, 0);

  // 5) chunked selective scan (64 chunks x 16 steps), Asum = y1+y2 bf16
  scan_a<<<dim3(4, 64, 8), dim3(256), 0, stream>>>(deltab, xcb, dbc, a_tab, cs);
  scan_b<<<dim3(16, 4, 8), dim3(256), 0, stream>>>(cs);
  scan_c<<<dim3(4, 64, 4), dim3(256), 0, stream>>>(deltab, xcb, dbc, a_tab, Dp, cs, Asum);

  // 6) K6: out[b] = Asum[b] @ zT[b] + x[b]
  gemm_mfma<3, 64, 64><<<dim3(16, 16, 4), dim3(256), 0, stream>>>(
      Asum, zTb, nullptr, x, out, nullptr,
      1024, 1024, 1024, 1024, 0, 0,
      M1, M1, M1, M1, 0, 0);
}